// Round 20
// baseline (41.597 us; speedup 1.0000x reference)
//
#include <hip/hip_runtime.h>
#include <hip/hip_bf16.h>

// Problem constants
#define IH 4096
#define IW 4096
#define KH 11
#define KW 11
#define OH (IH - KH + 1)   // 4086
#define OW (IW - KW + 1)   // 4086

// Block tile: 64x64 outputs, 8 waves (512 threads).
// Wave wv -> row band (wv>>1)*16, col half (wv&1)*32 (2 c-tiles of 16).
#define BM 64
#define BN 64
#define TROWS   74               // staged input rows (64 + 10 halo)
#define FSTRIDE 84               // f32 per LDS row: 336B = 21 x 16B chunks.
                                 // 84 mod 32 = 20 -> 8 bank residues over 16
                                 // rows => ~2-way on A b128 reads (near-free)
#define NCH_ROW 21               // 16B chunks per row (20 data + 1 dead pad)
#define NCHUNK  (TROWS * NCH_ROW)     // 1554
#define TILE_FLOATS (TROWS * FSTRIDE) // 6216 f32 = 24864 B
#define BMAT_SHORTS (KH * 512)        // 11264 B
// LDS: 24864 + 11264 = 36128 B -> 4 blocks/CU x 8 waves = 32-wave ceiling

#define TILES_X 64
#define NTILE   4096

typedef short bf16x8 __attribute__((ext_vector_type(8)));
typedef float f32x4  __attribute__((ext_vector_type(4)));

__device__ __forceinline__ short f2b(float f) {
    __hip_bfloat16 h = __float2bfloat16(f);   // RNE
    return __builtin_bit_cast(short, h);
}

// ---- setup kernel (r17-r19): banded-Toeplitz B in global scratch ----
// B_kh[k][j] = w[kh][k-j] (banded), stored [kh][j][k]: lane frag = 16B chunk.
__global__ void build_bmat(const float* __restrict__ w, short* __restrict__ bm) {
    const int tid = threadIdx.x;
#pragma unroll
    for (int t = 0; t < 22; ++t) {             // 22*256 = 5632 exact
        const int idx = tid + t * 256;
        const int kh = idx >> 9;
        const int j  = (idx >> 5) & 15;
        const int k  = idx & 31;
        const int d  = k - j;
        const float val = (d >= 0 && d < KW) ? w[kh * KW + d] : 0.f;
        bm[idx] = f2b(val);
    }
}

// ---- A-fragment load: 2x b128 f32 from LDS + cvt to bf16x8 (RNE, same
// numerics as the old staging cvt). Compiler emits v_cvt_pk_bf16_f32. ----
__device__ __forceinline__ void loadA2cvt(bf16x8 a[2], const float* __restrict__ ap) {
#pragma unroll
    for (int c = 0; c < 2; ++c) {
        f32x4 p = *reinterpret_cast<const f32x4*>(ap + c * 16);
        f32x4 q = *reinterpret_cast<const f32x4*>(ap + c * 16 + 4);
        bf16x8 v;
#pragma unroll
        for (int e = 0; e < 4; ++e) { v[e] = f2b(p[e]); v[4 + e] = f2b(q[e]); }
        a[c] = v;
    }
}

__device__ __forceinline__ void mfma2(f32x4 acc[2], const bf16x8 a[2], bf16x8 b) {
#pragma unroll
    for (int c = 0; c < 2; ++c) {
        acc[c] = __builtin_amdgcn_mfma_f32_16x16x32_bf16(a[c], b, acc[c], 0, 0, 0);
    }
}

// Single-tile block with DMA staging (global_load_lds width=16):
// no VGPR round-trip, no staging cvt burst, no ds_write issue — the tile
// streams into LDS on the VMEM pipe while the wave falls through to the
// B-copy; ONE implicit drain at the barrier. f32->bf16 happens on A-read.
// Per-lane SOURCE clamp handles edges: clamped (garbage) rows/cols feed
// only outputs with oy>=OH / ox>=OW, which are store-guarded (cols >= 64
// local feed only ox >= gx0+54+10 = 4086 at the last block column).
__global__ __launch_bounds__(512)
void conv2d_dma(const float* __restrict__ x,
                const short* __restrict__ bg,
                const float* __restrict__ bias,
                float* __restrict__ out) {
    __shared__ float tile[TILE_FLOATS];     // 24864 B, linear 16B chunks
    __shared__ short bmat[BMAT_SHORTS];     // 11264 B

    const int tid = threadIdx.x;
    // XCD-bijective swizzle (4096 % 8 == 0): each XCD gets 512 contiguous
    // tiles = 8 full tile rows -> halo re-reads hit the same L2.
    const int blk = (blockIdx.x & 7) * (NTILE / 8) + (blockIdx.x >> 3);
    const int gy0 = (blk >> 6) * BM;
    const int gx0 = (blk & (TILES_X - 1)) * BN;

    const int lane = tid & 63;
    const int wvb  = tid & ~63;     // wave's chunk base within an iteration

    // ---- DMA staging: chunk i -> LDS bytes [16i, 16i+16); src per-lane ----
#pragma unroll
    for (int it = 0; it < 4; ++it) {
        const int i = tid + it * 512;
        if (i < NCHUNK) {
            const int r  = i / NCH_ROW;
            const int c4 = i - r * NCH_ROW;
            const int gy = gy0 + r;
            const int gx = gx0 + c4 * 4;
            const float* src = (c4 < 20 && gy < IH && gx + 3 < IW)
                               ? (x + (size_t)gy * IW + gx) : x;  // clamp
            __builtin_amdgcn_global_load_lds(
                (const __attribute__((address_space(1))) void*)src,
                (__attribute__((address_space(3))) void*)&tile[(it * 512 + wvb) * 4],
                16, 0, 0);
        }
    }
    // ---- Copy B matrices from global scratch (L2-hot, 16B chunks) ----
#pragma unroll
    for (int t = 0; t < 2; ++t) {              // 704 int4 chunks
        const int idx = tid + t * 512;
        if (idx < (BMAT_SHORTS * 2) / 16) {
            reinterpret_cast<int4*>(bmat)[idx] =
                reinterpret_cast<const int4*>(bg)[idx];
        }
    }
    __syncthreads();   // drains the DMA (vmcnt) + publishes bmat

    // ---- Pipelined MFMA compute (r15/r19 core; A now f32->cvt-on-read) ----
    // out[oy0+i][ox0+j] = sum_kh A_kh*B_kh; A_kh[i][k] = X[oy0+kh+i][ox0+k],
    // B_kh[k][j] = w[kh][k-j]. A row = lane&15, B col = lane&15,
    // C/D col=lane&15,row=(lane>>4)*4+reg.
    const int wv = tid >> 6;        // 0..7
    const int wr = wv >> 1;         // row band 0..3
    const int ch = wv & 1;          // col half 0..1
    const int g  = lane >> 4;
    const int li = lane & 15;
    const float bv = bias[0];

    f32x4 acc[2] = {};
    const float* ap = &tile[(16 * wr + li) * FSTRIDE + ch * 32 + g * 8];
    const short* bp = &bmat[li * 32 + g * 8];

    bf16x8 Ae[2], Ao[2], Be, Bo;
    loadA2cvt(Ae, ap);                                    // kh = 0
    Be = *reinterpret_cast<const bf16x8*>(bp);

#pragma unroll 1
    for (int kh2 = 0; kh2 < 5; ++kh2) {
        loadA2cvt(Ao, ap + FSTRIDE);                      // kh odd
        Bo = *reinterpret_cast<const bf16x8*>(bp + 512);
        mfma2(acc, Ae, Be);                               // compute even
        ap += 2 * FSTRIDE;
        bp += 1024;
        loadA2cvt(Ae, ap);                                // kh next even
        Be = *reinterpret_cast<const bf16x8*>(bp);
        mfma2(acc, Ao, Bo);                               // compute odd
    }
    mfma2(acc, Ae, Be);                                   // kh = 10

    // ---- Write back ----
#pragma unroll
    for (int c = 0; c < 2; ++c) {
        const int ox = gx0 + ch * 32 + c * 16 + li;
        if (ox < OW) {
#pragma unroll
            for (int r = 0; r < 4; ++r) {
                const int oy = gy0 + wr * 16 + g * 4 + r;
                if (oy < OH) {
                    out[(size_t)oy * OW + ox] = acc[c][r] + bv;
                }
            }
        }
    }
}

extern "C" void kernel_launch(void* const* d_in, const int* in_sizes, int n_in,
                              void* d_out, int out_size, void* d_ws, size_t ws_size,
                              hipStream_t stream) {
    const float* x    = (const float*)d_in[0];
    const float* w    = (const float*)d_in[1];
    const float* bias = (const float*)d_in[2];
    float* out        = (float*)d_out;
    short* bm         = (short*)d_ws;        // 11264 B of scratch

    build_bmat<<<dim3(1), dim3(256), 0, stream>>>(w, bm);

    dim3 grid(NTILE);     // 4096 single-tile blocks
    dim3 block(512);
    conv2d_dma<<<grid, block, 0, stream>>>(x, bm, bias, out);
}